// Round 14
// baseline (638.898 us; speedup 1.0000x reference)
//
#include <hip/hip_runtime.h>
#include <hip/hip_cooperative_groups.h>
#include <math.h>

namespace cg = cooperative_groups;

#define HH 1536
#define WW 1536
#define HWSZ (HH*WW)

typedef __attribute__((ext_vector_type(8))) short bf16x8;
typedef __attribute__((ext_vector_type(4))) float f32x4;
#define MFMA16 __builtin_amdgcn_mfma_f32_16x16x32_bf16

struct Scalars {
  float gsum[4];
  float gsumsq[4];
};

#define OFF_F3    0UL
#define OFF_FUSED 75497472UL
#define OFF_SC    84934656UL
#define OFF_GHA   (OFF_SC + 1024UL)
#define OFF_GHB   (OFF_GHA + 2048UL*4UL)
#define OFF_GHC   (OFF_GHB + 4UL*2048UL*4UL)
#define OFF_WP    (OFF_GHC + 4UL*1024UL*4UL)
#define WS_NEEDED (OFF_WP + 38UL*512UL*2UL)
#define ZWORDS 14592   // (1024 + 8192 + 32768 + 16384)/4 bytes of sc+ghA+ghB+ghC

__device__ __forceinline__ short f2bf(float f) {
  unsigned u = __float_as_uint(f);
  unsigned r = (u + 0x7FFFu + ((u >> 16) & 1u)) >> 16;
  return (short)(unsigned short)r;
}
__device__ __forceinline__ float bf2f(short s) {
  return __uint_as_float(((unsigned)(unsigned short)s) << 16);
}
// truncation hi/lo split: h=trunc16(v), l=trunc16(v - h)
__device__ __forceinline__ void tsplit(float v, short &h, short &l) {
  unsigned u = __float_as_uint(v);
  h = (short)(u >> 16);
  float r = v - __uint_as_float(u & 0xffff0000u);
  l = (short)(__float_as_uint(r) >> 16);
}
__device__ __forceinline__ float leaky_f(float v) { return v >= 0.f ? v : 0.2f*v; }

// ---------------- weight prepack (split bf16 hi/lo, RNE) + workspace zeroing ----------------
__global__ __launch_bounds__(256) void k_pack(const float* __restrict__ w1,
    const float* __restrict__ w2, const float* __restrict__ w3, short* __restrict__ wp,
    unsigned* __restrict__ zr) {
  int idx = blockIdx.x*256 + threadIdx.x;
  if (idx < ZWORDS) zr[idx] = 0;
  if (idx >= 38*512) return;
  int blk = idx >> 9, e = idx & 511;
  int oc = e >> 5, k = e & 31;
  float v = 0.f; int plane = 0;
  if (blk < 8) {
    plane = blk & 1; int sl = (blk >> 1) & 1, half = blk >> 2;
    int pos = sl*8 + (k >> 2), ic = k & 3;
    if (pos < 9) v = w1[((16*half + oc)*4 + ic)*9 + pos];
  } else if (blk < 28) {
    int t = blk - 8; plane = t & 1; int hs = t >> 1;
    int half = hs / 5, sl = hs % 5;
    int p = k >> 4, icl = k & 15;
    int pos = 2*sl + p;
    if (pos < 9) v = w2[(oc*32 + half*16 + icl)*9 + pos];
  } else {
    int t = blk - 28; plane = t & 1; int sl = t >> 1;
    int pos = 2*sl + (k >> 4), ic = k & 15;
    if (oc < 8 && pos < 9) v = w3[(oc*16 + ic)*9 + pos];
  }
  short h = f2bf(v);
  wp[idx] = plane ? f2bf(v - bf2f(h)) : h;
}

// ---------------- fused conv chain; f1 half-resident, 8-ch SoA planes ----------------
__global__ __launch_bounds__(256, 3) void k_conv(
    const float* __restrict__ x,
    const float* __restrict__ b1, const float* __restrict__ b2, const float* __restrict__ b3,
    const short* __restrict__ wp, float* __restrict__ f3, Scalars* __restrict__ sc)
{
  __shared__ __align__(16) short smem[23168];
  __shared__ float red[32];
  short* f1h  = smem;            // planes at 0 / 3200
  short* f1l  = smem + 6400;     // planes at 6400 / 9600
  short* xs_h = smem + 12800;    // [484][4]   (dies after conv1 h1)
  short* xs_l = smem + 14736;
  short* f2h  = smem + 12800;    // planes at 12800 / 15392
  short* f2l  = smem + 17984;    // planes at 17984 / 20576

  const int tid  = threadIdx.x;
  const int lane = tid & 63;
  const int wv   = tid >> 6;
  const int pl   = lane & 15;
  const int g    = lane >> 4;
  const int x0 = blockIdx.x * 16, y0 = blockIdx.y * 16;

  float st[8];
  #pragma unroll
  for (int k = 0; k < 8; ++k) st[k] = 0.f;
  for (int i = tid; i < 484; i += 256) {
    int ry = i / 22, rx = i % 22;
    int gy = y0 - 3 + ry, gx = x0 - 3 + rx;
    bool ok = ((unsigned)gy < HH) && ((unsigned)gx < WW);
    bool interior = (ry >= 3) && (ry < 19) && (rx >= 3) && (rx < 19);
    int off = gy*WW + gx;
    short4 hv, lv;
    #pragma unroll
    for (int ic = 0; ic < 4; ++ic) {
      float v = ok ? x[ic*HWSZ + off] : 0.f;
      if (interior) { st[ic*2] += v; st[ic*2+1] += v*v; }
      short h, l; tsplit(v, h, l);
      ((short*)&hv)[ic] = h;
      ((short*)&lv)[ic] = l;
    }
    *(short4*)&xs_h[i*4] = hv;
    *(short4*)&xs_l[i*4] = lv;
  }
  #pragma unroll
  for (int k = 0; k < 8; ++k) {
    for (int o = 32; o; o >>= 1) st[k] += __shfl_down(st[k], o, 64);
  }
  if (lane == 0) {
    #pragma unroll
    for (int k = 0; k < 8; ++k) red[wv*8 + k] = st[k];
  }
  __syncthreads();
  if (tid < 8) {
    float t = red[tid] + red[8+tid] + red[16+tid] + red[24+tid];
    int ch = tid >> 1;
    if (tid & 1) atomicAdd(&sc->gsumsq[ch], t);
    else         atomicAdd(&sc->gsum[ch],   t);
  }

  int c1ry[7], c1rx[7];
  #pragma unroll
  for (int n = 0; n < 7; ++n) {
    int G = wv + 4*n; if (G > 24) G = 24;
    int px = 16*G + pl;
    c1ry[n] = px / 20; c1rx[n] = px % 20;
  }
  int ryA[6], rxA[6];
  #pragma unroll
  for (int n = 0; n < 6; ++n) {
    int G = wv + 4*n; if (G > 20) G = 20;
    int px = 16*G + pl; if (px > 323) px = 323;
    ryA[n] = px / 18; rxA[n] = px % 18;
  }

  f32x4 acc2[6];
  {
    float4 bb = *(const float4*)&b2[4*g];
    #pragma unroll
    for (int n = 0; n < 6; ++n) acc2[n] = f32x4{bb.x, bb.y, bb.z, bb.w};
  }

  auto conv1_half = [&](int half) {
    f32x4 acc[7];
    float4 bb = *(const float4*)&b1[16*half + 4*g];
    #pragma unroll
    for (int n = 0; n < 7; ++n) acc[n] = f32x4{bb.x, bb.y, bb.z, bb.w};
    for (int sl = 0; sl < 2; ++sl) {
      const short* wb = wp + (size_t)((half*2 + sl)*2)*512;
      bf16x8 wh = *(const bf16x8*)(wb + pl*32 + 8*g);
      bf16x8 wl = *(const bf16x8*)(wb + 512 + pl*32 + 8*g);
      if (sl == 0) {
        int p0 = 2*g, p1 = 2*g + 1;
        int dy0 = p0/3, dx0 = p0%3, dy1 = p1/3, dx1 = p1%3;
        #pragma unroll
        for (int n = 0; n < 7; ++n) {
          int i0 = (c1ry[n] + dy0)*22 + c1rx[n] + dx0;
          int i1 = (c1ry[n] + dy1)*22 + c1rx[n] + dx1;
          short4 h0 = *(const short4*)&xs_h[i0*4];
          short4 h1 = *(const short4*)&xs_h[i1*4];
          short4 l0 = *(const short4*)&xs_l[i0*4];
          short4 l1 = *(const short4*)&xs_l[i1*4];
          bf16x8 bh = {h0.x,h0.y,h0.z,h0.w,h1.x,h1.y,h1.z,h1.w};
          bf16x8 bl = {l0.x,l0.y,l0.z,l0.w,l1.x,l1.y,l1.z,l1.w};
          acc[n] = MFMA16(wh, bh, acc[n], 0,0,0);
          acc[n] = MFMA16(wh, bl, acc[n], 0,0,0);
          acc[n] = MFMA16(wl, bh, acc[n], 0,0,0);
        }
      } else {
        #pragma unroll
        for (int n = 0; n < 7; ++n) {
          short4 h8 = {0,0,0,0}, l8 = {0,0,0,0};
          if (g == 0) {
            int i8 = (c1ry[n] + 2)*22 + c1rx[n] + 2;
            h8 = *(const short4*)&xs_h[i8*4];
            l8 = *(const short4*)&xs_l[i8*4];
          }
          bf16x8 bh = {h8.x,h8.y,h8.z,h8.w,0,0,0,0};
          bf16x8 bl = {l8.x,l8.y,l8.z,l8.w,0,0,0,0};
          acc[n] = MFMA16(wh, bh, acc[n], 0,0,0);
          acc[n] = MFMA16(wh, bl, acc[n], 0,0,0);
          acc[n] = MFMA16(wl, bh, acc[n], 0,0,0);
        }
      }
    }
    #pragma unroll
    for (int n = 0; n < 7; ++n) {
      int G = wv + 4*n; if (G > 24) G = 24;
      int px = 16*G + pl;
      int gy = y0 - 2 + c1ry[n], gx = x0 - 2 + c1rx[n];
      bool ok = ((unsigned)gy < HH) && ((unsigned)gx < WW);
      short4 hv, lv;
      #pragma unroll
      for (int r = 0; r < 4; ++r) {
        float v = ok ? leaky_f(acc[n][r]) : 0.f;
        short h, l; tsplit(v, h, l);
        ((short*)&hv)[r] = h;
        ((short*)&lv)[r] = l;
      }
      int fo = (g>>1)*3200 + px*8 + (g&1)*4;
      *(short4*)&f1h[fo] = hv;
      *(short4*)&f1l[fo] = lv;
    }
  };

  auto conv2_part = [&](int half) {
    for (int s = 0; s < 5; ++s) {
      const short* wb = wp + (size_t)(8 + (half*5 + s)*2)*512;
      bf16x8 wh = *(const bf16x8*)(wb + pl*32 + 8*g);
      bf16x8 wl = *(const bf16x8*)(wb + 512 + pl*32 + 8*g);
      int pos = 2*s + (g >> 1);
      bool pv = pos < 9;
      int dy = pv ? pos/3 : 0, dx = pv ? pos%3 : 0;
      const int pb = (g&1)*3200;
      #pragma unroll
      for (int n = 0; n < 6; ++n) {
        int idx = (ryA[n] + dy)*20 + rxA[n] + dx;
        bf16x8 bh = {0,0,0,0,0,0,0,0}, bl = {0,0,0,0,0,0,0,0};
        if (pv) {
          int so = pb + idx*8;
          bh = *(const bf16x8*)&f1h[so];
          bl = *(const bf16x8*)&f1l[so];
        }
        acc2[n] = MFMA16(wh, bh, acc2[n], 0,0,0);
        acc2[n] = MFMA16(wh, bl, acc2[n], 0,0,0);
        acc2[n] = MFMA16(wl, bh, acc2[n], 0,0,0);
      }
    }
  };

  conv1_half(0);
  __syncthreads();
  conv2_part(0);
  __syncthreads();
  conv1_half(1);
  __syncthreads();
  conv2_part(1);
  #pragma unroll
  for (int n = 0; n < 6; ++n) {
    int G = wv + 4*n; if (G > 20) G = 20;
    int px = 16*G + pl;
    if (px < 324) {
      int gy = y0 - 1 + ryA[n], gx = x0 - 1 + rxA[n];
      bool ok = ((unsigned)gy < HH) && ((unsigned)gx < WW);
      short4 hv, lv;
      #pragma unroll
      for (int r = 0; r < 4; ++r) {
        float v = ok ? leaky_f(acc2[n][r]) : 0.f;
        short h, l; tsplit(v, h, l);
        ((short*)&hv)[r] = h;
        ((short*)&lv)[r] = l;
      }
      int fo = (g>>1)*2592 + px*8 + (g&1)*4;
      *(short4*)&f2h[fo] = hv;
      *(short4*)&f2l[fo] = lv;
    }
  }
  __syncthreads();

  // ---- conv3: 16->8 (plane = g&1) ----
  {
    f32x4 acc[4];
    float4 bb;
    if (g < 2) bb = *(const float4*)&b3[4*g];
    else { bb.x = 0.f; bb.y = 0.f; bb.z = 0.f; bb.w = 0.f; }
    #pragma unroll
    for (int n = 0; n < 4; ++n) acc[n] = f32x4{bb.x, bb.y, bb.z, bb.w};
    for (int s = 0; s < 5; ++s) {
      const short* wb = wp + (size_t)(28 + s*2)*512;
      bf16x8 wh = *(const bf16x8*)(wb + pl*32 + 8*g);
      bf16x8 wl = *(const bf16x8*)(wb + 512 + pl*32 + 8*g);
      int pos = 2*s + (g >> 1);
      bool pv = pos < 9;
      int dy = pv ? pos/3 : 0, dx = pv ? pos%3 : 0;
      const int pb = (g&1)*2592;
      #pragma unroll
      for (int n = 0; n < 4; ++n) {
        int px = 16*(wv + 4*n) + pl;
        int ry = px >> 4, rx = px & 15;
        int idx = (ry + dy)*18 + rx + dx;
        bf16x8 bh = {0,0,0,0,0,0,0,0}, bl = {0,0,0,0,0,0,0,0};
        if (pv) {
          int so = pb + idx*8;
          bh = *(const bf16x8*)&f2h[so];
          bl = *(const bf16x8*)&f2l[so];
        }
        acc[n] = MFMA16(wh, bh, acc[n], 0,0,0);
        acc[n] = MFMA16(wh, bl, acc[n], 0,0,0);
        acc[n] = MFMA16(wl, bh, acc[n], 0,0,0);
      }
    }
    #pragma unroll
    for (int n = 0; n < 4; ++n) {
      int px = 16*(wv + 4*n) + pl;
      int ry = px >> 4, rx = px & 15;
      size_t base = (size_t)(y0 + ry)*WW + (x0 + rx);
      #pragma unroll
      for (int r = 0; r < 4; ++r) {
        int oc = 4*g + r;
        if (oc < 8) f3[(size_t)oc*HWSZ + base] = acc[n][r];
      }
    }
  }
}

// ---------------- std maps: 32x32 tile, dual SATs, channel prefetch, fused histA ----------------
#define SATW 82
__device__ __forceinline__ float satv(const float* __restrict__ S, int r, int c) {
  return (r < 0 || c < 0) ? 0.f : S[r*SATW + c];
}
__device__ __forceinline__ float boxsum(const float* __restrict__ S, int r1, int r2, int c1, int c2) {
  return satv(S, r2, c2) - satv(S, r1-1, c2) - satv(S, r2, c1-1) + satv(S, r1-1, c1-1);
}

__global__ __launch_bounds__(256) void k_std(
    const float* __restrict__ f3, const float* __restrict__ wf,
    const float* __restrict__ bfp, float* __restrict__ fused, unsigned* __restrict__ ghA)
{
  __shared__ __align__(8) float S1[80*SATW];
  __shared__ __align__(8) float S2[80*SATW];
  const int tid = threadIdx.x;
  const int x0 = blockIdx.x * 32, y0 = blockIdx.y * 32;

  int off[25];
  #pragma unroll
  for (int it = 0; it < 25; ++it) {
    const int idx = tid + 256*it;
    const int r = idx / 80, cc = idx - r*80;
    int gy = y0 - 24 + r;  gy = gy < 0 ? -gy : (gy >= HH ? 2*HH - 2 - gy : gy);
    int gx = x0 - 24 + cc; gx = gx < 0 ? -gx : (gx >= WW ? 2*WW - 2 - gx : gx);
    off[it] = gy*WW + gx;
  }

  float pf[25];
  #pragma unroll
  for (int it = 0; it < 25; ++it) pf[it] = f3[off[it]];

  float acc0[4], acc1[4], acc2[4];
  #pragma unroll
  for (int k = 0; k < 4; ++k) { acc0[k] = 0.f; acc1[k] = 0.f; acc2[k] = 0.f; }

  for (int ch = 0; ch < 8; ++ch) {
    #pragma unroll
    for (int it = 0; it < 25; ++it) {
      const int idx = tid + 256*it;
      const int si = idx + 2*(idx/80);
      const float v = pf[it];
      S1[si] = v;
      S2[si] = v*v;
    }
    __syncthreads();
    if (ch < 7) {
      const float* fn = f3 + (size_t)(ch+1)*HWSZ;
      #pragma unroll
      for (int it = 0; it < 25; ++it) pf[it] = fn[off[it]];
    }
    if (tid < 160) {
      float* row = (tid >= 80 ? S2 + (tid-80)*SATW : S1 + tid*SATW);
      float run = 0.f;
      #pragma unroll
      for (int q = 0; q < 40; ++q) {
        float2 v = *(float2*)&row[q*2];
        float a = run + v.x;
        float b = a + v.y;
        float2 st = {a, b};
        *(float2*)&row[q*2] = st;
        run = b;
      }
    }
    __syncthreads();
    if (tid < 160) {
      float* Sc = (tid >= 80 ? S2 + (tid-80) : S1 + tid);
      float run = 0.f;
      #pragma unroll
      for (int g4 = 0; g4 < 20; ++g4) {
        float v0 = Sc[(g4*4+0)*SATW];
        float v1 = Sc[(g4*4+1)*SATW];
        float v2 = Sc[(g4*4+2)*SATW];
        float v3 = Sc[(g4*4+3)*SATW];
        run += v0; Sc[(g4*4+0)*SATW] = run;
        run += v1; Sc[(g4*4+1)*SATW] = run;
        run += v2; Sc[(g4*4+2)*SATW] = run;
        run += v3; Sc[(g4*4+3)*SATW] = run;
      }
    }
    __syncthreads();
    #pragma unroll
    for (int k = 0; k < 4; ++k) {
      const int px = tid + 256*k;
      const int py = px >> 5, xx = px & 31;
      {
        const float invn = 1.f/121.f;
        const float s1 = boxsum(S1, py+19, py+29, xx+19, xx+29);
        const float s2 = boxsum(S2, py+19, py+29, xx+19, xx+29);
        const float m = s1*invn;
        acc0[k] += sqrtf(fmaxf(s2*invn - m*m, 1e-6f));
      }
      {
        const float invn = 1.f/625.f;
        const float s1 = boxsum(S1, py+12, py+36, xx+12, xx+36);
        const float s2 = boxsum(S2, py+12, py+36, xx+12, xx+36);
        const float m = s1*invn;
        acc1[k] += sqrtf(fmaxf(s2*invn - m*m, 1e-6f));
      }
      {
        const float invn = 1.f/2401.f;
        const float s1 = boxsum(S1, py, py+48, xx, xx+48);
        const float s2 = boxsum(S2, py, py+48, xx, xx+48);
        const float m = s1*invn;
        acc2[k] += sqrtf(fmaxf(s2*invn - m*m, 1e-6f));
      }
    }
    __syncthreads();
  }

  unsigned* lh = (unsigned*)S1;
  for (int i = tid; i < 2048; i += 256) lh[i] = 0;
  __syncthreads();
  const float wv0 = wf[0], wv1 = wf[1], wv2 = wf[2], bv = bfp[0];
  #pragma unroll
  for (int k = 0; k < 4; ++k) {
    const int px = tid + 256*k;
    const int py = px >> 5, xx = px & 31;
    const float r0 = acc0[k]*0.125f, r1 = acc1[k]*0.125f, r2 = acc2[k]*0.125f;
    const float p0 = exp2f(0.8f*log2f(r0));
    const float p1 = exp2f(0.8f*log2f(r1));
    const float p2 = exp2f(0.8f*log2f(r2));
    float f = wv0*p0 + wv1*p1 + wv2*p2 + bv;
    f = fmaxf(f, 0.f);
    fused[(size_t)(y0 + py)*WW + (x0 + xx)] = f;
    atomicAdd(&lh[__float_as_uint(f) >> 21], 1u);
  }
  __syncthreads();
  for (int i = tid; i < 2048; i += 256) if (lh[i]) atomicAdd(&ghA[i], lh[i]);
}

// ---------------- radix select ----------------
__device__ bool scan_select(const unsigned* __restrict__ hist, int per, unsigned rank,
                            unsigned& bin, unsigned& inner) {
  const int lane = threadIdx.x & 63;
  const int base = lane * per;
  unsigned s = 0;
  for (int j = 0; j < per; ++j) s += hist[base + j];
  unsigned v = s;
  for (int off = 1; off < 64; off <<= 1) {
    unsigned n = __shfl_up(v, off, 64);
    if (lane >= off) v += n;
  }
  const unsigned excl = v - s;
  const bool has = (rank >= excl) && (rank < v);
  const unsigned long long m = __ballot(has);
  const int L = __ffsll(m) - 1;
  if (lane == L) {
    unsigned rem = rank - excl;
    for (int j = 0; j < per; ++j) {
      const unsigned c = hist[base + j];
      if (rem < c) { bin = (unsigned)(base + j); inner = rem; return true; }
      rem -= c;
    }
  }
  return false;
}

__device__ __forceinline__ float seg_sig(float ns) {
  ns = fminf(fmaxf(ns, 0.f), 1.f);
  float res;
  if (ns < 0.25f)      res = 0.4f / (1.f + expf(-(10.f*ns - 1.5f)));
  else if (ns <= 0.6f) res = 0.5f / (1.f + expf(-(20.f*ns - 8.f))) + 0.25f;
  else                 res = 0.3f / (1.f + expf(-(8.f*ns - 1.f))) + 0.7f;
  return res;
}

__device__ void tail_thresholds(const Scalars* sc, const float* cwp,
    float q_low, float q_high, float* ths) {
  const float c0 = cwp[0], c1 = cwp[1], c2 = cwp[2], c3 = cwp[3];
  const float mx = fmaxf(fmaxf(c0, c1), fmaxf(c2, c3));
  const float e0 = expf(c0 - mx), e1 = expf(c1 - mx), e2 = expf(c2 - mx), e3 = expf(c3 - mx);
  const float es = e0 + e1 + e2 + e3;
  const float cw[4] = {e0/es, e1/es, e2/es, e3/es};
  const double N = (double)HWSZ;
  float lsum = 0.f, usum = 0.f;
  for (int c = 0; c < 4; ++c) {
    double var = ((double)sc->gsumsq[c] - (double)sc->gsum[c]*(double)sc->gsum[c]/N) / (N - 1.0);
    if (var < 0.0) var = 0.0;
    const float gs = (float)sqrt(var);
    const float gf = fminf(fmaxf(gs*5.f, 0.5f), 2.f);
    float lt = 0.05f*gf, ut = 0.2f*gf;
    const float cs = cw[c]*gs;
    const float cf = fminf(fmaxf(cs*2.f, 0.8f), 1.2f);
    lt *= cf; ut *= cf;
    lsum += lt; usum += ut;
  }
  float l_th = 0.5f*(lsum*0.25f + q_low);
  float u_th = 0.5f*(usum*0.25f + q_high);
  if (u_th - l_th < 0.01f) u_th = l_th + 0.01f;
  ths[0] = l_th; ths[1] = u_th;
}

// ---------------- cooperative tail: histB + histC + apply in one launch ----------------
__global__ __launch_bounds__(256) void k_tail(const float* __restrict__ fused,
    const Scalars* __restrict__ sc, const float* __restrict__ cwp,
    unsigned* __restrict__ ghA, unsigned* __restrict__ ghB, unsigned* __restrict__ ghC,
    float* __restrict__ out,
    unsigned r0, unsigned r1, unsigned r2, unsigned r3, float fr_lo, float fr_hi) {
  cg::grid_group grid = cg::this_grid();
  __shared__ unsigned lh[8192];
  __shared__ unsigned t1s[4], in1s[4], t2s[4], in2s[4];
  __shared__ float vqs[4], ths[2];
  const int tid = threadIdx.x;
  const int w = tid >> 6;
  const unsigned rk = (w == 0) ? r0 : (w == 1) ? r1 : (w == 2) ? r2 : r3;

  // ---- phase 1: histB ----
  {
    unsigned bin, inner;
    if (scan_select(ghA, 32, rk, bin, inner)) { t1s[w] = bin; in1s[w] = inner; }
  }
  for (int i = tid; i < 8192; i += 256) lh[i] = 0;
  __syncthreads();
  {
    const unsigned a0 = t1s[0], a1 = t1s[1], a2 = t1s[2], a3 = t1s[3];
    for (int i = blockIdx.x*256 + tid; i < HWSZ; i += 1024*256) {
      const unsigned u = __float_as_uint(fused[i]);
      const unsigned p = u >> 21, b = (u >> 10) & 2047u;
      if (p == a0) atomicAdd(&lh[b], 1u);
      if (p == a1) atomicAdd(&lh[2048 + b], 1u);
      if (p == a2) atomicAdd(&lh[4096 + b], 1u);
      if (p == a3) atomicAdd(&lh[6144 + b], 1u);
    }
  }
  __syncthreads();
  for (int i = tid; i < 8192; i += 256) if (lh[i]) atomicAdd(&ghB[i], lh[i]);
  grid.sync();

  // ---- phase 2: histC ----
  {
    unsigned bin, inner;
    if (scan_select(ghB + w*2048, 32, in1s[w], bin, inner)) {
      t2s[w] = (t1s[w] << 11) | bin; in2s[w] = inner;
    }
  }
  for (int i = tid; i < 4096; i += 256) lh[i] = 0;
  __syncthreads();
  {
    const unsigned c0 = t2s[0], c1 = t2s[1], c2 = t2s[2], c3 = t2s[3];
    for (int i = blockIdx.x*256 + tid; i < HWSZ; i += 1024*256) {
      const unsigned u = __float_as_uint(fused[i]);
      const unsigned p = u >> 10, b = u & 1023u;
      if (p == c0) atomicAdd(&lh[b], 1u);
      if (p == c1) atomicAdd(&lh[1024 + b], 1u);
      if (p == c2) atomicAdd(&lh[2048 + b], 1u);
      if (p == c3) atomicAdd(&lh[3072 + b], 1u);
    }
  }
  __syncthreads();
  for (int i = tid; i < 4096; i += 256) if (lh[i]) atomicAdd(&ghC[i], lh[i]);
  grid.sync();

  // ---- phase 3: final select + thresholds + apply ----
  {
    unsigned bin, inner;
    if (scan_select(ghC + w*1024, 16, in2s[w], bin, inner))
      vqs[w] = __uint_as_float((t2s[w] << 10) | bin);
  }
  __syncthreads();
  if (tid == 0) {
    const float q_low  = vqs[0] + fr_lo * (vqs[1] - vqs[0]);
    const float q_high = vqs[2] + fr_hi * (vqs[3] - vqs[2]);
    tail_thresholds(sc, cwp, q_low, q_high, ths);
  }
  __syncthreads();
  const float l = ths[0], u = ths[1];
  const float d = u - l;
  for (int i = blockIdx.x*256 + tid; i < HWSZ/4; i += 1024*256) {
    const float4 v = ((const float4*)fused)[i];
    float4 r;
    r.x = seg_sig((v.x - l) / d);
    r.y = seg_sig((v.y - l) / d);
    r.z = seg_sig((v.z - l) / d);
    r.w = seg_sig((v.w - l) / d);
    ((float4*)out)[i] = r;
  }
}

// ---------------- fallback tail (3 kernels, same math) ----------------
__global__ __launch_bounds__(256) void k_histB(const float* __restrict__ fused,
    const unsigned* __restrict__ ghA, unsigned* __restrict__ gh,
    unsigned r0, unsigned r1, unsigned r2, unsigned r3) {
  __shared__ unsigned lh[4*2048];
  __shared__ unsigned t1s[4];
  {
    const int w = threadIdx.x >> 6;
    const unsigned rk = (w == 0) ? r0 : (w == 1) ? r1 : (w == 2) ? r2 : r3;
    unsigned bin, inner;
    if (scan_select(ghA, 32, rk, bin, inner)) t1s[w] = bin;
  }
  for (int i = threadIdx.x; i < 8192; i += 256) lh[i] = 0;
  __syncthreads();
  const unsigned t0 = t1s[0], t1 = t1s[1], t2 = t1s[2], t3 = t1s[3];
  for (int i = blockIdx.x*256 + threadIdx.x; i < HWSZ; i += 512*256) {
    const unsigned u = __float_as_uint(fused[i]);
    const unsigned p = u >> 21, b = (u >> 10) & 2047u;
    if (p == t0) atomicAdd(&lh[b], 1u);
    if (p == t1) atomicAdd(&lh[2048 + b], 1u);
    if (p == t2) atomicAdd(&lh[4096 + b], 1u);
    if (p == t3) atomicAdd(&lh[6144 + b], 1u);
  }
  __syncthreads();
  for (int i = threadIdx.x; i < 8192; i += 256) if (lh[i]) atomicAdd(&gh[i], lh[i]);
}

__global__ __launch_bounds__(256) void k_histC(const float* __restrict__ fused,
    const unsigned* __restrict__ ghA, const unsigned* __restrict__ ghB,
    unsigned* __restrict__ gh, unsigned r0, unsigned r1, unsigned r2, unsigned r3) {
  __shared__ unsigned lh[4*1024];
  __shared__ unsigned t1s[4], in1s[4], t2s[4];
  const int w = threadIdx.x >> 6;
  {
    const unsigned rk = (w == 0) ? r0 : (w == 1) ? r1 : (w == 2) ? r2 : r3;
    unsigned bin, inner;
    if (scan_select(ghA, 32, rk, bin, inner)) { t1s[w] = bin; in1s[w] = inner; }
  }
  __syncthreads();
  {
    unsigned bin, inner;
    if (scan_select(ghB + w*2048, 32, in1s[w], bin, inner))
      t2s[w] = (t1s[w] << 11) | bin;
  }
  for (int i = threadIdx.x; i < 4096; i += 256) lh[i] = 0;
  __syncthreads();
  const unsigned t0 = t2s[0], t1 = t2s[1], t2 = t2s[2], t3 = t2s[3];
  for (int i = blockIdx.x*256 + threadIdx.x; i < HWSZ; i += 512*256) {
    const unsigned u = __float_as_uint(fused[i]);
    const unsigned p = u >> 10, b = u & 1023u;
    if (p == t0) atomicAdd(&lh[b], 1u);
    if (p == t1) atomicAdd(&lh[1024 + b], 1u);
    if (p == t2) atomicAdd(&lh[2048 + b], 1u);
    if (p == t3) atomicAdd(&lh[3072 + b], 1u);
  }
  __syncthreads();
  for (int i = threadIdx.x; i < 4096; i += 256) if (lh[i]) atomicAdd(&gh[i], lh[i]);
}

__global__ __launch_bounds__(256) void k_apply(const float* __restrict__ fused,
    const Scalars* __restrict__ sc, const float* __restrict__ cwp,
    const unsigned* __restrict__ ghA, const unsigned* __restrict__ ghB,
    const unsigned* __restrict__ ghC, float* __restrict__ out,
    unsigned r0, unsigned r1, unsigned r2, unsigned r3, float fr_lo, float fr_hi) {
  __shared__ unsigned t1s[4], in1s[4], t2s[4], in2s[4];
  __shared__ float vqs[4];
  __shared__ float ths[2];
  const int w = threadIdx.x >> 6;
  {
    const unsigned rk = (w == 0) ? r0 : (w == 1) ? r1 : (w == 2) ? r2 : r3;
    unsigned bin, inner;
    if (scan_select(ghA, 32, rk, bin, inner)) { t1s[w] = bin; in1s[w] = inner; }
  }
  __syncthreads();
  {
    unsigned bin, inner;
    if (scan_select(ghB + w*2048, 32, in1s[w], bin, inner)) {
      t2s[w] = (t1s[w] << 11) | bin; in2s[w] = inner;
    }
  }
  __syncthreads();
  {
    unsigned bin, inner;
    if (scan_select(ghC + w*1024, 16, in2s[w], bin, inner))
      vqs[w] = __uint_as_float((t2s[w] << 10) | bin);
  }
  __syncthreads();
  if (threadIdx.x == 0) {
    const float q_low  = vqs[0] + fr_lo * (vqs[1] - vqs[0]);
    const float q_high = vqs[2] + fr_hi * (vqs[3] - vqs[2]);
    tail_thresholds(sc, cwp, q_low, q_high, ths);
  }
  __syncthreads();
  const float l = ths[0], u = ths[1];
  const float d = u - l;
  const int i = blockIdx.x*256 + threadIdx.x;
  if (i < HWSZ/4) {
    const float4 v = ((const float4*)fused)[i];
    float4 r;
    r.x = seg_sig((v.x - l) / d);
    r.y = seg_sig((v.y - l) / d);
    r.z = seg_sig((v.z - l) / d);
    r.w = seg_sig((v.w - l) / d);
    ((float4*)out)[i] = r;
  }
}

extern "C" void kernel_launch(void* const* d_in, const int* in_sizes, int n_in,
                              void* d_out, int out_size, void* d_ws, size_t ws_size,
                              hipStream_t stream) {
  const float* x  = (const float*)d_in[0];
  const float* w1 = (const float*)d_in[1];
  const float* b1 = (const float*)d_in[2];
  const float* w2 = (const float*)d_in[3];
  const float* b2 = (const float*)d_in[4];
  const float* w3 = (const float*)d_in[5];
  const float* b3 = (const float*)d_in[6];
  const float* wf = (const float*)d_in[7];
  const float* bf = (const float*)d_in[8];
  const float* cw = (const float*)d_in[9];
  char* ws = (char*)d_ws;
  if (ws_size < WS_NEEDED) return;

  float*    f3    = (float*)(ws + OFF_F3);
  float*    fused = (float*)(ws + OFF_FUSED);
  Scalars*  sc    = (Scalars*)(ws + OFF_SC);
  unsigned* ghA   = (unsigned*)(ws + OFF_GHA);
  unsigned* ghB   = (unsigned*)(ws + OFF_GHB);
  unsigned* ghC   = (unsigned*)(ws + OFF_GHC);
  short*    wp    = (short*)(ws + OFF_WP);
  unsigned* zr    = (unsigned*)(ws + OFF_SC);

  const double p_lo = 0.3 * (double)(HWSZ - 1);
  const double p_hi = 0.7 * (double)(HWSZ - 1);
  const unsigned k0 = (unsigned)p_lo, k1 = (unsigned)p_hi;
  float fr_lo = (float)(p_lo - (double)k0);
  float fr_hi = (float)(p_hi - (double)k1);
  unsigned r0 = k0, r1 = k0 + 1, r2 = k1, r3 = k1 + 1;

  k_pack <<<76, 256, 0, stream>>>(w1, w2, w3, wp, zr);
  k_conv <<<dim3(96, 96), 256, 0, stream>>>(x, b1, b2, b3, wp, f3, sc);
  k_std  <<<dim3(48, 48), 256, 0, stream>>>(f3, wf, bf, fused, ghA);

  const float* fusedc = fused;
  const Scalars* scc = sc;
  float* outp = (float*)d_out;
  void* args[] = {(void*)&fusedc, (void*)&scc, (void*)&cw, (void*)&ghA, (void*)&ghB,
                  (void*)&ghC, (void*)&outp, (void*)&r0, (void*)&r1, (void*)&r2,
                  (void*)&r3, (void*)&fr_lo, (void*)&fr_hi};
  hipError_t e = hipLaunchCooperativeKernel((void*)k_tail, dim3(1024), dim3(256),
                                            args, 0, stream);
  if (e != hipSuccess) {
    k_histB<<<512, 256, 0, stream>>>(fused, ghA, ghB, r0, r1, r2, r3);
    k_histC<<<512, 256, 0, stream>>>(fused, ghA, ghB, ghC, r0, r1, r2, r3);
    k_apply<<<(HWSZ/4 + 255)/256, 256, 0, stream>>>(fused, sc, cw, ghA, ghB, ghC,
        outp, r0, r1, r2, r3, fr_lo, fr_hi);
  }
}

// Round 15
// 480.782 us; speedup vs baseline: 1.3289x; 1.3289x over previous
//
#include <hip/hip_runtime.h>
#include <math.h>

#define HH 1536
#define WW 1536
#define HWSZ (HH*WW)

typedef __attribute__((ext_vector_type(8))) short bf16x8;
typedef __attribute__((ext_vector_type(4))) float f32x4;
#define MFMA16 __builtin_amdgcn_mfma_f32_16x16x32_bf16

struct Scalars {
  float gsum[4];
  float gsumsq[4];
};

#define OFF_F3    0UL
#define OFF_FUSED 75497472UL
#define OFF_SC    84934656UL
#define OFF_GHA   (OFF_SC + 1024UL)
#define OFF_GHB   (OFF_GHA + 2048UL*4UL)
#define OFF_GHC   (OFF_GHB + 4UL*2048UL*4UL)
#define OFF_WP    (OFF_GHC + 4UL*1024UL*4UL)
#define WS_NEEDED (OFF_WP + 38UL*512UL*2UL)
#define ZWORDS 14592   // (1024 + 8192 + 32768 + 16384)/4 bytes of sc+ghA+ghB+ghC

__device__ __forceinline__ short f2bf(float f) {
  unsigned u = __float_as_uint(f);
  unsigned r = (u + 0x7FFFu + ((u >> 16) & 1u)) >> 16;
  return (short)(unsigned short)r;
}
__device__ __forceinline__ float bf2f(short s) {
  return __uint_as_float(((unsigned)(unsigned short)s) << 16);
}
// truncation hi/lo split: h=trunc16(v), l=trunc16(v - h)
__device__ __forceinline__ void tsplit(float v, short &h, short &l) {
  unsigned u = __float_as_uint(v);
  h = (short)(u >> 16);
  float r = v - __uint_as_float(u & 0xffff0000u);
  l = (short)(__float_as_uint(r) >> 16);
}
__device__ __forceinline__ float leaky_f(float v) { return v >= 0.f ? v : 0.2f*v; }

// ---------------- weight prepack (split bf16 hi/lo, RNE) + workspace zeroing ----------------
__global__ __launch_bounds__(256) void k_pack(const float* __restrict__ w1,
    const float* __restrict__ w2, const float* __restrict__ w3, short* __restrict__ wp,
    unsigned* __restrict__ zr) {
  int idx = blockIdx.x*256 + threadIdx.x;
  if (idx < ZWORDS) zr[idx] = 0;
  if (idx >= 38*512) return;
  int blk = idx >> 9, e = idx & 511;
  int oc = e >> 5, k = e & 31;
  float v = 0.f; int plane = 0;
  if (blk < 8) {
    plane = blk & 1; int sl = (blk >> 1) & 1, half = blk >> 2;
    int pos = sl*8 + (k >> 2), ic = k & 3;
    if (pos < 9) v = w1[((16*half + oc)*4 + ic)*9 + pos];
  } else if (blk < 28) {
    int t = blk - 8; plane = t & 1; int hs = t >> 1;
    int half = hs / 5, sl = hs % 5;
    int p = k >> 4, icl = k & 15;
    int pos = 2*sl + p;
    if (pos < 9) v = w2[(oc*32 + half*16 + icl)*9 + pos];
  } else {
    int t = blk - 28; plane = t & 1; int sl = t >> 1;
    int pos = 2*sl + (k >> 4), ic = k & 15;
    if (oc < 8 && pos < 9) v = w3[(oc*16 + ic)*9 + pos];
  }
  short h = f2bf(v);
  wp[idx] = plane ? f2bf(v - bf2f(h)) : h;
}

// ---------------- fused conv chain; f1 half-resident, 8-ch SoA planes ----------------
__global__ __launch_bounds__(256, 3) void k_conv(
    const float* __restrict__ x,
    const float* __restrict__ b1, const float* __restrict__ b2, const float* __restrict__ b3,
    const short* __restrict__ wp, float* __restrict__ f3, Scalars* __restrict__ sc)
{
  __shared__ __align__(16) short smem[23168];
  __shared__ float red[32];
  short* f1h  = smem;            // planes at 0 / 3200
  short* f1l  = smem + 6400;     // planes at 6400 / 9600
  short* xs_h = smem + 12800;    // [484][4]   (dies after conv1 h1)
  short* xs_l = smem + 14736;
  short* f2h  = smem + 12800;    // planes at 12800 / 15392
  short* f2l  = smem + 17984;    // planes at 17984 / 20576

  const int tid  = threadIdx.x;
  const int lane = tid & 63;
  const int wv   = tid >> 6;
  const int pl   = lane & 15;
  const int g    = lane >> 4;
  const int x0 = blockIdx.x * 16, y0 = blockIdx.y * 16;

  float st[8];
  #pragma unroll
  for (int k = 0; k < 8; ++k) st[k] = 0.f;
  for (int i = tid; i < 484; i += 256) {
    int ry = i / 22, rx = i % 22;
    int gy = y0 - 3 + ry, gx = x0 - 3 + rx;
    bool ok = ((unsigned)gy < HH) && ((unsigned)gx < WW);
    bool interior = (ry >= 3) && (ry < 19) && (rx >= 3) && (rx < 19);
    int off = gy*WW + gx;
    short4 hv, lv;
    #pragma unroll
    for (int ic = 0; ic < 4; ++ic) {
      float v = ok ? x[ic*HWSZ + off] : 0.f;
      if (interior) { st[ic*2] += v; st[ic*2+1] += v*v; }
      short h, l; tsplit(v, h, l);
      ((short*)&hv)[ic] = h;
      ((short*)&lv)[ic] = l;
    }
    *(short4*)&xs_h[i*4] = hv;
    *(short4*)&xs_l[i*4] = lv;
  }
  #pragma unroll
  for (int k = 0; k < 8; ++k) {
    for (int o = 32; o; o >>= 1) st[k] += __shfl_down(st[k], o, 64);
  }
  if (lane == 0) {
    #pragma unroll
    for (int k = 0; k < 8; ++k) red[wv*8 + k] = st[k];
  }
  __syncthreads();
  if (tid < 8) {
    float t = red[tid] + red[8+tid] + red[16+tid] + red[24+tid];
    int ch = tid >> 1;
    if (tid & 1) atomicAdd(&sc->gsumsq[ch], t);
    else         atomicAdd(&sc->gsum[ch],   t);
  }

  int c1ry[7], c1rx[7];
  #pragma unroll
  for (int n = 0; n < 7; ++n) {
    int G = wv + 4*n; if (G > 24) G = 24;
    int px = 16*G + pl;
    c1ry[n] = px / 20; c1rx[n] = px % 20;
  }
  int ryA[6], rxA[6];
  #pragma unroll
  for (int n = 0; n < 6; ++n) {
    int G = wv + 4*n; if (G > 20) G = 20;
    int px = 16*G + pl; if (px > 323) px = 323;
    ryA[n] = px / 18; rxA[n] = px % 18;
  }

  f32x4 acc2[6];
  {
    float4 bb = *(const float4*)&b2[4*g];
    #pragma unroll
    for (int n = 0; n < 6; ++n) acc2[n] = f32x4{bb.x, bb.y, bb.z, bb.w};
  }

  auto conv1_half = [&](int half) {
    f32x4 acc[7];
    float4 bb = *(const float4*)&b1[16*half + 4*g];
    #pragma unroll
    for (int n = 0; n < 7; ++n) acc[n] = f32x4{bb.x, bb.y, bb.z, bb.w};
    for (int sl = 0; sl < 2; ++sl) {
      const short* wb = wp + (size_t)((half*2 + sl)*2)*512;
      bf16x8 wh = *(const bf16x8*)(wb + pl*32 + 8*g);
      bf16x8 wl = *(const bf16x8*)(wb + 512 + pl*32 + 8*g);
      if (sl == 0) {
        int p0 = 2*g, p1 = 2*g + 1;
        int dy0 = p0/3, dx0 = p0%3, dy1 = p1/3, dx1 = p1%3;
        #pragma unroll
        for (int n = 0; n < 7; ++n) {
          int i0 = (c1ry[n] + dy0)*22 + c1rx[n] + dx0;
          int i1 = (c1ry[n] + dy1)*22 + c1rx[n] + dx1;
          short4 h0 = *(const short4*)&xs_h[i0*4];
          short4 h1 = *(const short4*)&xs_h[i1*4];
          short4 l0 = *(const short4*)&xs_l[i0*4];
          short4 l1 = *(const short4*)&xs_l[i1*4];
          bf16x8 bh = {h0.x,h0.y,h0.z,h0.w,h1.x,h1.y,h1.z,h1.w};
          bf16x8 bl = {l0.x,l0.y,l0.z,l0.w,l1.x,l1.y,l1.z,l1.w};
          acc[n] = MFMA16(wh, bh, acc[n], 0,0,0);
          acc[n] = MFMA16(wh, bl, acc[n], 0,0,0);
          acc[n] = MFMA16(wl, bh, acc[n], 0,0,0);
        }
      } else {
        #pragma unroll
        for (int n = 0; n < 7; ++n) {
          short4 h8 = {0,0,0,0}, l8 = {0,0,0,0};
          if (g == 0) {
            int i8 = (c1ry[n] + 2)*22 + c1rx[n] + 2;
            h8 = *(const short4*)&xs_h[i8*4];
            l8 = *(const short4*)&xs_l[i8*4];
          }
          bf16x8 bh = {h8.x,h8.y,h8.z,h8.w,0,0,0,0};
          bf16x8 bl = {l8.x,l8.y,l8.z,l8.w,0,0,0,0};
          acc[n] = MFMA16(wh, bh, acc[n], 0,0,0);
          acc[n] = MFMA16(wh, bl, acc[n], 0,0,0);
          acc[n] = MFMA16(wl, bh, acc[n], 0,0,0);
        }
      }
    }
    #pragma unroll
    for (int n = 0; n < 7; ++n) {
      int G = wv + 4*n; if (G > 24) G = 24;
      int px = 16*G + pl;
      int gy = y0 - 2 + c1ry[n], gx = x0 - 2 + c1rx[n];
      bool ok = ((unsigned)gy < HH) && ((unsigned)gx < WW);
      short4 hv, lv;
      #pragma unroll
      for (int r = 0; r < 4; ++r) {
        float v = ok ? leaky_f(acc[n][r]) : 0.f;
        short h, l; tsplit(v, h, l);
        ((short*)&hv)[r] = h;
        ((short*)&lv)[r] = l;
      }
      int fo = (g>>1)*3200 + px*8 + (g&1)*4;
      *(short4*)&f1h[fo] = hv;
      *(short4*)&f1l[fo] = lv;
    }
  };

  auto conv2_part = [&](int half) {
    for (int s = 0; s < 5; ++s) {
      const short* wb = wp + (size_t)(8 + (half*5 + s)*2)*512;
      bf16x8 wh = *(const bf16x8*)(wb + pl*32 + 8*g);
      bf16x8 wl = *(const bf16x8*)(wb + 512 + pl*32 + 8*g);
      int pos = 2*s + (g >> 1);
      bool pv = pos < 9;
      int dy = pv ? pos/3 : 0, dx = pv ? pos%3 : 0;
      const int pb = (g&1)*3200;
      #pragma unroll
      for (int n = 0; n < 6; ++n) {
        int idx = (ryA[n] + dy)*20 + rxA[n] + dx;
        bf16x8 bh = {0,0,0,0,0,0,0,0}, bl = {0,0,0,0,0,0,0,0};
        if (pv) {
          int so = pb + idx*8;
          bh = *(const bf16x8*)&f1h[so];
          bl = *(const bf16x8*)&f1l[so];
        }
        acc2[n] = MFMA16(wh, bh, acc2[n], 0,0,0);
        acc2[n] = MFMA16(wh, bl, acc2[n], 0,0,0);
        acc2[n] = MFMA16(wl, bh, acc2[n], 0,0,0);
      }
    }
  };

  conv1_half(0);
  __syncthreads();
  conv2_part(0);
  __syncthreads();
  conv1_half(1);
  __syncthreads();
  conv2_part(1);
  #pragma unroll
  for (int n = 0; n < 6; ++n) {
    int G = wv + 4*n; if (G > 20) G = 20;
    int px = 16*G + pl;
    if (px < 324) {
      int gy = y0 - 1 + ryA[n], gx = x0 - 1 + rxA[n];
      bool ok = ((unsigned)gy < HH) && ((unsigned)gx < WW);
      short4 hv, lv;
      #pragma unroll
      for (int r = 0; r < 4; ++r) {
        float v = ok ? leaky_f(acc2[n][r]) : 0.f;
        short h, l; tsplit(v, h, l);
        ((short*)&hv)[r] = h;
        ((short*)&lv)[r] = l;
      }
      int fo = (g>>1)*2592 + px*8 + (g&1)*4;
      *(short4*)&f2h[fo] = hv;
      *(short4*)&f2l[fo] = lv;
    }
  }
  __syncthreads();

  // ---- conv3: 16->8 (plane = g&1) ----
  {
    f32x4 acc[4];
    float4 bb;
    if (g < 2) bb = *(const float4*)&b3[4*g];
    else { bb.x = 0.f; bb.y = 0.f; bb.z = 0.f; bb.w = 0.f; }
    #pragma unroll
    for (int n = 0; n < 4; ++n) acc[n] = f32x4{bb.x, bb.y, bb.z, bb.w};
    for (int s = 0; s < 5; ++s) {
      const short* wb = wp + (size_t)(28 + s*2)*512;
      bf16x8 wh = *(const bf16x8*)(wb + pl*32 + 8*g);
      bf16x8 wl = *(const bf16x8*)(wb + 512 + pl*32 + 8*g);
      int pos = 2*s + (g >> 1);
      bool pv = pos < 9;
      int dy = pv ? pos/3 : 0, dx = pv ? pos%3 : 0;
      const int pb = (g&1)*2592;
      #pragma unroll
      for (int n = 0; n < 4; ++n) {
        int px = 16*(wv + 4*n) + pl;
        int ry = px >> 4, rx = px & 15;
        int idx = (ry + dy)*18 + rx + dx;
        bf16x8 bh = {0,0,0,0,0,0,0,0}, bl = {0,0,0,0,0,0,0,0};
        if (pv) {
          int so = pb + idx*8;
          bh = *(const bf16x8*)&f2h[so];
          bl = *(const bf16x8*)&f2l[so];
        }
        acc[n] = MFMA16(wh, bh, acc[n], 0,0,0);
        acc[n] = MFMA16(wh, bl, acc[n], 0,0,0);
        acc[n] = MFMA16(wl, bh, acc[n], 0,0,0);
      }
    }
    #pragma unroll
    for (int n = 0; n < 4; ++n) {
      int px = 16*(wv + 4*n) + pl;
      int ry = px >> 4, rx = px & 15;
      size_t base = (size_t)(y0 + ry)*WW + (x0 + rx);
      #pragma unroll
      for (int r = 0; r < 4; ++r) {
        int oc = 4*g + r;
        if (oc < 8) f3[(size_t)oc*HWSZ + base] = acc[n][r];
      }
    }
  }
}

// ---------------- std maps: 32x32 tile, dual SATs, channel prefetch, fused histA ----------------
#define SATW 82
__device__ __forceinline__ float satv(const float* __restrict__ S, int r, int c) {
  return (r < 0 || c < 0) ? 0.f : S[r*SATW + c];
}
__device__ __forceinline__ float boxsum(const float* __restrict__ S, int r1, int r2, int c1, int c2) {
  return satv(S, r2, c2) - satv(S, r1-1, c2) - satv(S, r2, c1-1) + satv(S, r1-1, c1-1);
}

__global__ __launch_bounds__(256) void k_std(
    const float* __restrict__ f3, const float* __restrict__ wf,
    const float* __restrict__ bfp, float* __restrict__ fused, unsigned* __restrict__ ghA)
{
  __shared__ __align__(8) float S1[80*SATW];
  __shared__ __align__(8) float S2[80*SATW];
  const int tid = threadIdx.x;
  const int x0 = blockIdx.x * 32, y0 = blockIdx.y * 32;

  int off[25];
  #pragma unroll
  for (int it = 0; it < 25; ++it) {
    const int idx = tid + 256*it;
    const int r = idx / 80, cc = idx - r*80;
    int gy = y0 - 24 + r;  gy = gy < 0 ? -gy : (gy >= HH ? 2*HH - 2 - gy : gy);
    int gx = x0 - 24 + cc; gx = gx < 0 ? -gx : (gx >= WW ? 2*WW - 2 - gx : gx);
    off[it] = gy*WW + gx;
  }

  float pf[25];
  #pragma unroll
  for (int it = 0; it < 25; ++it) pf[it] = f3[off[it]];

  float acc0[4], acc1[4], acc2[4];
  #pragma unroll
  for (int k = 0; k < 4; ++k) { acc0[k] = 0.f; acc1[k] = 0.f; acc2[k] = 0.f; }

  for (int ch = 0; ch < 8; ++ch) {
    #pragma unroll
    for (int it = 0; it < 25; ++it) {
      const int idx = tid + 256*it;
      const int si = idx + 2*(idx/80);
      const float v = pf[it];
      S1[si] = v;
      S2[si] = v*v;
    }
    __syncthreads();
    if (ch < 7) {
      const float* fn = f3 + (size_t)(ch+1)*HWSZ;
      #pragma unroll
      for (int it = 0; it < 25; ++it) pf[it] = fn[off[it]];
    }
    if (tid < 160) {
      float* row = (tid >= 80 ? S2 + (tid-80)*SATW : S1 + tid*SATW);
      float run = 0.f;
      #pragma unroll
      for (int q = 0; q < 40; ++q) {
        float2 v = *(float2*)&row[q*2];
        float a = run + v.x;
        float b = a + v.y;
        float2 st = {a, b};
        *(float2*)&row[q*2] = st;
        run = b;
      }
    }
    __syncthreads();
    if (tid < 160) {
      float* Sc = (tid >= 80 ? S2 + (tid-80) : S1 + tid);
      float run = 0.f;
      #pragma unroll
      for (int g4 = 0; g4 < 20; ++g4) {
        float v0 = Sc[(g4*4+0)*SATW];
        float v1 = Sc[(g4*4+1)*SATW];
        float v2 = Sc[(g4*4+2)*SATW];
        float v3 = Sc[(g4*4+3)*SATW];
        run += v0; Sc[(g4*4+0)*SATW] = run;
        run += v1; Sc[(g4*4+1)*SATW] = run;
        run += v2; Sc[(g4*4+2)*SATW] = run;
        run += v3; Sc[(g4*4+3)*SATW] = run;
      }
    }
    __syncthreads();
    #pragma unroll
    for (int k = 0; k < 4; ++k) {
      const int px = tid + 256*k;
      const int py = px >> 5, xx = px & 31;
      {
        const float invn = 1.f/121.f;
        const float s1 = boxsum(S1, py+19, py+29, xx+19, xx+29);
        const float s2 = boxsum(S2, py+19, py+29, xx+19, xx+29);
        const float m = s1*invn;
        acc0[k] += sqrtf(fmaxf(s2*invn - m*m, 1e-6f));
      }
      {
        const float invn = 1.f/625.f;
        const float s1 = boxsum(S1, py+12, py+36, xx+12, xx+36);
        const float s2 = boxsum(S2, py+12, py+36, xx+12, xx+36);
        const float m = s1*invn;
        acc1[k] += sqrtf(fmaxf(s2*invn - m*m, 1e-6f));
      }
      {
        const float invn = 1.f/2401.f;
        const float s1 = boxsum(S1, py, py+48, xx, xx+48);
        const float s2 = boxsum(S2, py, py+48, xx, xx+48);
        const float m = s1*invn;
        acc2[k] += sqrtf(fmaxf(s2*invn - m*m, 1e-6f));
      }
    }
    __syncthreads();
  }

  unsigned* lh = (unsigned*)S1;
  for (int i = tid; i < 2048; i += 256) lh[i] = 0;
  __syncthreads();
  const float wv0 = wf[0], wv1 = wf[1], wv2 = wf[2], bv = bfp[0];
  #pragma unroll
  for (int k = 0; k < 4; ++k) {
    const int px = tid + 256*k;
    const int py = px >> 5, xx = px & 31;
    const float r0 = acc0[k]*0.125f, r1 = acc1[k]*0.125f, r2 = acc2[k]*0.125f;
    const float p0 = exp2f(0.8f*log2f(r0));
    const float p1 = exp2f(0.8f*log2f(r1));
    const float p2 = exp2f(0.8f*log2f(r2));
    float f = wv0*p0 + wv1*p1 + wv2*p2 + bv;
    f = fmaxf(f, 0.f);
    fused[(size_t)(y0 + py)*WW + (x0 + xx)] = f;
    atomicAdd(&lh[__float_as_uint(f) >> 21], 1u);
  }
  __syncthreads();
  for (int i = tid; i < 2048; i += 256) if (lh[i]) atomicAdd(&ghA[i], lh[i]);
}

// ---------------- radix select ----------------
__device__ bool scan_select(const unsigned* __restrict__ hist, int per, unsigned rank,
                            unsigned& bin, unsigned& inner) {
  const int lane = threadIdx.x & 63;
  const int base = lane * per;
  unsigned s = 0;
  for (int j = 0; j < per; ++j) s += hist[base + j];
  unsigned v = s;
  for (int off = 1; off < 64; off <<= 1) {
    unsigned n = __shfl_up(v, off, 64);
    if (lane >= off) v += n;
  }
  const unsigned excl = v - s;
  const bool has = (rank >= excl) && (rank < v);
  const unsigned long long m = __ballot(has);
  const int L = __ffsll(m) - 1;
  if (lane == L) {
    unsigned rem = rank - excl;
    for (int j = 0; j < per; ++j) {
      const unsigned c = hist[base + j];
      if (rem < c) { bin = (unsigned)(base + j); inner = rem; return true; }
      rem -= c;
    }
  }
  return false;
}

__device__ __forceinline__ float seg_sig(float ns) {
  ns = fminf(fmaxf(ns, 0.f), 1.f);
  float res;
  if (ns < 0.25f)      res = 0.4f / (1.f + expf(-(10.f*ns - 1.5f)));
  else if (ns <= 0.6f) res = 0.5f / (1.f + expf(-(20.f*ns - 8.f))) + 0.25f;
  else                 res = 0.3f / (1.f + expf(-(8.f*ns - 1.f))) + 0.7f;
  return res;
}

__device__ void tail_thresholds(const Scalars* sc, const float* cwp,
    float q_low, float q_high, float* ths) {
  const float c0 = cwp[0], c1 = cwp[1], c2 = cwp[2], c3 = cwp[3];
  const float mx = fmaxf(fmaxf(c0, c1), fmaxf(c2, c3));
  const float e0 = expf(c0 - mx), e1 = expf(c1 - mx), e2 = expf(c2 - mx), e3 = expf(c3 - mx);
  const float es = e0 + e1 + e2 + e3;
  const float cw[4] = {e0/es, e1/es, e2/es, e3/es};
  const double N = (double)HWSZ;
  float lsum = 0.f, usum = 0.f;
  for (int c = 0; c < 4; ++c) {
    double var = ((double)sc->gsumsq[c] - (double)sc->gsum[c]*(double)sc->gsum[c]/N) / (N - 1.0);
    if (var < 0.0) var = 0.0;
    const float gs = (float)sqrt(var);
    const float gf = fminf(fmaxf(gs*5.f, 0.5f), 2.f);
    float lt = 0.05f*gf, ut = 0.2f*gf;
    const float cs = cw[c]*gs;
    const float cf = fminf(fmaxf(cs*2.f, 0.8f), 1.2f);
    lt *= cf; ut *= cf;
    lsum += lt; usum += ut;
  }
  float l_th = 0.5f*(lsum*0.25f + q_low);
  float u_th = 0.5f*(usum*0.25f + q_high);
  if (u_th - l_th < 0.01f) u_th = l_th + 0.01f;
  ths[0] = l_th; ths[1] = u_th;
}

__global__ __launch_bounds__(256) void k_histB(const float* __restrict__ fused,
    const unsigned* __restrict__ ghA, unsigned* __restrict__ gh,
    unsigned r0, unsigned r1, unsigned r2, unsigned r3) {
  __shared__ unsigned lh[4*2048];
  __shared__ unsigned t1s[4];
  {
    const int w = threadIdx.x >> 6;
    const unsigned rk = (w == 0) ? r0 : (w == 1) ? r1 : (w == 2) ? r2 : r3;
    unsigned bin, inner;
    if (scan_select(ghA, 32, rk, bin, inner)) t1s[w] = bin;
  }
  for (int i = threadIdx.x; i < 8192; i += 256) lh[i] = 0;
  __syncthreads();
  const unsigned t0 = t1s[0], t1 = t1s[1], t2 = t1s[2], t3 = t1s[3];
  for (int i = blockIdx.x*256 + threadIdx.x; i < HWSZ; i += 512*256) {
    const unsigned u = __float_as_uint(fused[i]);
    const unsigned p = u >> 21, b = (u >> 10) & 2047u;
    if (p == t0) atomicAdd(&lh[b], 1u);
    if (p == t1) atomicAdd(&lh[2048 + b], 1u);
    if (p == t2) atomicAdd(&lh[4096 + b], 1u);
    if (p == t3) atomicAdd(&lh[6144 + b], 1u);
  }
  __syncthreads();
  for (int i = threadIdx.x; i < 8192; i += 256) if (lh[i]) atomicAdd(&gh[i], lh[i]);
}

__global__ __launch_bounds__(256) void k_histC(const float* __restrict__ fused,
    const unsigned* __restrict__ ghA, const unsigned* __restrict__ ghB,
    unsigned* __restrict__ gh, unsigned r0, unsigned r1, unsigned r2, unsigned r3) {
  __shared__ unsigned lh[4*1024];
  __shared__ unsigned t1s[4], in1s[4], t2s[4];
  const int w = threadIdx.x >> 6;
  {
    const unsigned rk = (w == 0) ? r0 : (w == 1) ? r1 : (w == 2) ? r2 : r3;
    unsigned bin, inner;
    if (scan_select(ghA, 32, rk, bin, inner)) { t1s[w] = bin; in1s[w] = inner; }
  }
  __syncthreads();
  {
    unsigned bin, inner;
    if (scan_select(ghB + w*2048, 32, in1s[w], bin, inner))
      t2s[w] = (t1s[w] << 11) | bin;
  }
  for (int i = threadIdx.x; i < 4096; i += 256) lh[i] = 0;
  __syncthreads();
  const unsigned t0 = t2s[0], t1 = t2s[1], t2 = t2s[2], t3 = t2s[3];
  for (int i = blockIdx.x*256 + threadIdx.x; i < HWSZ; i += 512*256) {
    const unsigned u = __float_as_uint(fused[i]);
    const unsigned p = u >> 10, b = u & 1023u;
    if (p == t0) atomicAdd(&lh[b], 1u);
    if (p == t1) atomicAdd(&lh[1024 + b], 1u);
    if (p == t2) atomicAdd(&lh[2048 + b], 1u);
    if (p == t3) atomicAdd(&lh[3072 + b], 1u);
  }
  __syncthreads();
  for (int i = threadIdx.x; i < 4096; i += 256) if (lh[i]) atomicAdd(&gh[i], lh[i]);
}

__global__ __launch_bounds__(256) void k_apply(const float* __restrict__ fused,
    const Scalars* __restrict__ sc, const float* __restrict__ cwp,
    const unsigned* __restrict__ ghA, const unsigned* __restrict__ ghB,
    const unsigned* __restrict__ ghC, float* __restrict__ out,
    unsigned r0, unsigned r1, unsigned r2, unsigned r3, float fr_lo, float fr_hi) {
  __shared__ unsigned t1s[4], in1s[4], t2s[4], in2s[4];
  __shared__ float vqs[4];
  __shared__ float ths[2];
  const int w = threadIdx.x >> 6;
  {
    const unsigned rk = (w == 0) ? r0 : (w == 1) ? r1 : (w == 2) ? r2 : r3;
    unsigned bin, inner;
    if (scan_select(ghA, 32, rk, bin, inner)) { t1s[w] = bin; in1s[w] = inner; }
  }
  __syncthreads();
  {
    unsigned bin, inner;
    if (scan_select(ghB + w*2048, 32, in1s[w], bin, inner)) {
      t2s[w] = (t1s[w] << 11) | bin; in2s[w] = inner;
    }
  }
  __syncthreads();
  {
    unsigned bin, inner;
    if (scan_select(ghC + w*1024, 16, in2s[w], bin, inner))
      vqs[w] = __uint_as_float((t2s[w] << 10) | bin);
  }
  __syncthreads();
  if (threadIdx.x == 0) {
    const float q_low  = vqs[0] + fr_lo * (vqs[1] - vqs[0]);
    const float q_high = vqs[2] + fr_hi * (vqs[3] - vqs[2]);
    tail_thresholds(sc, cwp, q_low, q_high, ths);
  }
  __syncthreads();
  const float l = ths[0], u = ths[1];
  const float d = u - l;
  const int i = blockIdx.x*256 + threadIdx.x;
  if (i < HWSZ/4) {
    const float4 v = ((const float4*)fused)[i];
    float4 r;
    r.x = seg_sig((v.x - l) / d);
    r.y = seg_sig((v.y - l) / d);
    r.z = seg_sig((v.z - l) / d);
    r.w = seg_sig((v.w - l) / d);
    ((float4*)out)[i] = r;
  }
}

extern "C" void kernel_launch(void* const* d_in, const int* in_sizes, int n_in,
                              void* d_out, int out_size, void* d_ws, size_t ws_size,
                              hipStream_t stream) {
  const float* x  = (const float*)d_in[0];
  const float* w1 = (const float*)d_in[1];
  const float* b1 = (const float*)d_in[2];
  const float* w2 = (const float*)d_in[3];
  const float* b2 = (const float*)d_in[4];
  const float* w3 = (const float*)d_in[5];
  const float* b3 = (const float*)d_in[6];
  const float* wf = (const float*)d_in[7];
  const float* bf = (const float*)d_in[8];
  const float* cw = (const float*)d_in[9];
  char* ws = (char*)d_ws;
  if (ws_size < WS_NEEDED) return;

  float*    f3    = (float*)(ws + OFF_F3);
  float*    fused = (float*)(ws + OFF_FUSED);
  Scalars*  sc    = (Scalars*)(ws + OFF_SC);
  unsigned* ghA   = (unsigned*)(ws + OFF_GHA);
  unsigned* ghB   = (unsigned*)(ws + OFF_GHB);
  unsigned* ghC   = (unsigned*)(ws + OFF_GHC);
  short*    wp    = (short*)(ws + OFF_WP);
  unsigned* zr    = (unsigned*)(ws + OFF_SC);

  const double p_lo = 0.3 * (double)(HWSZ - 1);
  const double p_hi = 0.7 * (double)(HWSZ - 1);
  const unsigned k0 = (unsigned)p_lo, k1 = (unsigned)p_hi;
  const float fr_lo = (float)(p_lo - (double)k0);
  const float fr_hi = (float)(p_hi - (double)k1);

  k_pack <<<76, 256, 0, stream>>>(w1, w2, w3, wp, zr);
  k_conv <<<dim3(96, 96), 256, 0, stream>>>(x, b1, b2, b3, wp, f3, sc);
  k_std  <<<dim3(48, 48), 256, 0, stream>>>(f3, wf, bf, fused, ghA);
  k_histB<<<512, 256, 0, stream>>>(fused, ghA, ghB, k0, k0 + 1, k1, k1 + 1);
  k_histC<<<512, 256, 0, stream>>>(fused, ghA, ghB, ghC, k0, k0 + 1, k1, k1 + 1);
  k_apply<<<(HWSZ/4 + 255)/256, 256, 0, stream>>>(fused, sc, cw, ghA, ghB, ghC,
      (float*)d_out, k0, k0 + 1, k1, k1 + 1, fr_lo, fr_hi);
}

// Round 16
// 447.328 us; speedup vs baseline: 1.4283x; 1.0748x over previous
//
#include <hip/hip_runtime.h>
#include <math.h>

#define HH 1536
#define WW 1536
#define HWSZ (HH*WW)

typedef __attribute__((ext_vector_type(8))) short bf16x8;
typedef __attribute__((ext_vector_type(4))) float f32x4;
#define MFMA16 __builtin_amdgcn_mfma_f32_16x16x32_bf16

struct Scalars {
  float gsum[4];
  float gsumsq[4];
};

#define OFF_F3    0UL
#define OFF_FUSED 75497472UL
#define OFF_SC    84934656UL
#define OFF_GHA   (OFF_SC + 1024UL)
#define OFF_GHB   (OFF_GHA + 2048UL*4UL)
#define OFF_GHC   (OFF_GHB + 4UL*2048UL*4UL)
#define OFF_WP    (OFF_GHC + 4UL*1024UL*4UL)
#define WS_NEEDED (OFF_WP + 38UL*512UL*2UL)
#define ZWORDS 10496   // (1024 + 8192 + 32768)/4 bytes of sc+ghA+ghB

__device__ __forceinline__ short f2bf(float f) {
  unsigned u = __float_as_uint(f);
  unsigned r = (u + 0x7FFFu + ((u >> 16) & 1u)) >> 16;
  return (short)(unsigned short)r;
}
__device__ __forceinline__ float bf2f(short s) {
  return __uint_as_float(((unsigned)(unsigned short)s) << 16);
}
// truncation hi/lo split: h=trunc16(v), l=trunc16(v - h)
__device__ __forceinline__ void tsplit(float v, short &h, short &l) {
  unsigned u = __float_as_uint(v);
  h = (short)(u >> 16);
  float r = v - __uint_as_float(u & 0xffff0000u);
  l = (short)(__float_as_uint(r) >> 16);
}
__device__ __forceinline__ float leaky_f(float v) { return v >= 0.f ? v : 0.2f*v; }

// ---------------- weight prepack (split bf16 hi/lo, RNE) + workspace zeroing ----------------
__global__ __launch_bounds__(256) void k_pack(const float* __restrict__ w1,
    const float* __restrict__ w2, const float* __restrict__ w3, short* __restrict__ wp,
    unsigned* __restrict__ zr) {
  int idx = blockIdx.x*256 + threadIdx.x;
  if (idx < ZWORDS) zr[idx] = 0;
  if (idx >= 38*512) return;
  int blk = idx >> 9, e = idx & 511;
  int oc = e >> 5, k = e & 31;
  float v = 0.f; int plane = 0;
  if (blk < 8) {
    plane = blk & 1; int sl = (blk >> 1) & 1, half = blk >> 2;
    int pos = sl*8 + (k >> 2), ic = k & 3;
    if (pos < 9) v = w1[((16*half + oc)*4 + ic)*9 + pos];
  } else if (blk < 28) {
    int t = blk - 8; plane = t & 1; int hs = t >> 1;
    int half = hs / 5, sl = hs % 5;
    int p = k >> 4, icl = k & 15;
    int pos = 2*sl + p;
    if (pos < 9) v = w2[(oc*32 + half*16 + icl)*9 + pos];
  } else {
    int t = blk - 28; plane = t & 1; int sl = t >> 1;
    int pos = 2*sl + (k >> 4), ic = k & 15;
    if (oc < 8 && pos < 9) v = w3[(oc*16 + ic)*9 + pos];
  }
  short h = f2bf(v);
  wp[idx] = plane ? f2bf(v - bf2f(h)) : h;
}

// ---------------- fused conv chain; f1 half-resident, 8-ch SoA planes ----------------
__global__ __launch_bounds__(256, 3) void k_conv(
    const float* __restrict__ x,
    const float* __restrict__ b1, const float* __restrict__ b2, const float* __restrict__ b3,
    const short* __restrict__ wp, float* __restrict__ f3, Scalars* __restrict__ sc)
{
  __shared__ __align__(16) short smem[23168];
  __shared__ float red[32];
  short* f1h  = smem;            // planes at 0 / 3200
  short* f1l  = smem + 6400;     // planes at 6400 / 9600
  short* xs_h = smem + 12800;    // [484][4]   (dies after conv1 h1)
  short* xs_l = smem + 14736;
  short* f2h  = smem + 12800;    // planes at 12800 / 15392
  short* f2l  = smem + 17984;    // planes at 17984 / 20576

  const int tid  = threadIdx.x;
  const int lane = tid & 63;
  const int wv   = tid >> 6;
  const int pl   = lane & 15;
  const int g    = lane >> 4;
  const int x0 = blockIdx.x * 16, y0 = blockIdx.y * 16;

  float st[8];
  #pragma unroll
  for (int k = 0; k < 8; ++k) st[k] = 0.f;
  for (int i = tid; i < 484; i += 256) {
    int ry = i / 22, rx = i % 22;
    int gy = y0 - 3 + ry, gx = x0 - 3 + rx;
    bool ok = ((unsigned)gy < HH) && ((unsigned)gx < WW);
    bool interior = (ry >= 3) && (ry < 19) && (rx >= 3) && (rx < 19);
    int off = gy*WW + gx;
    short4 hv, lv;
    #pragma unroll
    for (int ic = 0; ic < 4; ++ic) {
      float v = ok ? x[ic*HWSZ + off] : 0.f;
      if (interior) { st[ic*2] += v; st[ic*2+1] += v*v; }
      short h, l; tsplit(v, h, l);
      ((short*)&hv)[ic] = h;
      ((short*)&lv)[ic] = l;
    }
    *(short4*)&xs_h[i*4] = hv;
    *(short4*)&xs_l[i*4] = lv;
  }
  #pragma unroll
  for (int k = 0; k < 8; ++k) {
    for (int o = 32; o; o >>= 1) st[k] += __shfl_down(st[k], o, 64);
  }
  if (lane == 0) {
    #pragma unroll
    for (int k = 0; k < 8; ++k) red[wv*8 + k] = st[k];
  }
  __syncthreads();
  if (tid < 8) {
    float t = red[tid] + red[8+tid] + red[16+tid] + red[24+tid];
    int ch = tid >> 1;
    if (tid & 1) atomicAdd(&sc->gsumsq[ch], t);
    else         atomicAdd(&sc->gsum[ch],   t);
  }

  int c1ry[7], c1rx[7];
  #pragma unroll
  for (int n = 0; n < 7; ++n) {
    int G = wv + 4*n; if (G > 24) G = 24;
    int px = 16*G + pl;
    c1ry[n] = px / 20; c1rx[n] = px % 20;
  }
  int ryA[6], rxA[6];
  #pragma unroll
  for (int n = 0; n < 6; ++n) {
    int G = wv + 4*n; if (G > 20) G = 20;
    int px = 16*G + pl; if (px > 323) px = 323;
    ryA[n] = px / 18; rxA[n] = px % 18;
  }

  f32x4 acc2[6];
  {
    float4 bb = *(const float4*)&b2[4*g];
    #pragma unroll
    for (int n = 0; n < 6; ++n) acc2[n] = f32x4{bb.x, bb.y, bb.z, bb.w};
  }

  auto conv1_half = [&](int half) {
    f32x4 acc[7];
    float4 bb = *(const float4*)&b1[16*half + 4*g];
    #pragma unroll
    for (int n = 0; n < 7; ++n) acc[n] = f32x4{bb.x, bb.y, bb.z, bb.w};
    for (int sl = 0; sl < 2; ++sl) {
      const short* wb = wp + (size_t)((half*2 + sl)*2)*512;
      bf16x8 wh = *(const bf16x8*)(wb + pl*32 + 8*g);
      bf16x8 wl = *(const bf16x8*)(wb + 512 + pl*32 + 8*g);
      if (sl == 0) {
        int p0 = 2*g, p1 = 2*g + 1;
        int dy0 = p0/3, dx0 = p0%3, dy1 = p1/3, dx1 = p1%3;
        #pragma unroll
        for (int n = 0; n < 7; ++n) {
          int i0 = (c1ry[n] + dy0)*22 + c1rx[n] + dx0;
          int i1 = (c1ry[n] + dy1)*22 + c1rx[n] + dx1;
          short4 h0 = *(const short4*)&xs_h[i0*4];
          short4 h1 = *(const short4*)&xs_h[i1*4];
          short4 l0 = *(const short4*)&xs_l[i0*4];
          short4 l1 = *(const short4*)&xs_l[i1*4];
          bf16x8 bh = {h0.x,h0.y,h0.z,h0.w,h1.x,h1.y,h1.z,h1.w};
          bf16x8 bl = {l0.x,l0.y,l0.z,l0.w,l1.x,l1.y,l1.z,l1.w};
          acc[n] = MFMA16(wh, bh, acc[n], 0,0,0);
          acc[n] = MFMA16(wh, bl, acc[n], 0,0,0);
          acc[n] = MFMA16(wl, bh, acc[n], 0,0,0);
        }
      } else {
        #pragma unroll
        for (int n = 0; n < 7; ++n) {
          short4 h8 = {0,0,0,0}, l8 = {0,0,0,0};
          if (g == 0) {
            int i8 = (c1ry[n] + 2)*22 + c1rx[n] + 2;
            h8 = *(const short4*)&xs_h[i8*4];
            l8 = *(const short4*)&xs_l[i8*4];
          }
          bf16x8 bh = {h8.x,h8.y,h8.z,h8.w,0,0,0,0};
          bf16x8 bl = {l8.x,l8.y,l8.z,l8.w,0,0,0,0};
          acc[n] = MFMA16(wh, bh, acc[n], 0,0,0);
          acc[n] = MFMA16(wh, bl, acc[n], 0,0,0);
          acc[n] = MFMA16(wl, bh, acc[n], 0,0,0);
        }
      }
    }
    #pragma unroll
    for (int n = 0; n < 7; ++n) {
      int G = wv + 4*n; if (G > 24) G = 24;
      int px = 16*G + pl;
      int gy = y0 - 2 + c1ry[n], gx = x0 - 2 + c1rx[n];
      bool ok = ((unsigned)gy < HH) && ((unsigned)gx < WW);
      short4 hv, lv;
      #pragma unroll
      for (int r = 0; r < 4; ++r) {
        float v = ok ? leaky_f(acc[n][r]) : 0.f;
        short h, l; tsplit(v, h, l);
        ((short*)&hv)[r] = h;
        ((short*)&lv)[r] = l;
      }
      int fo = (g>>1)*3200 + px*8 + (g&1)*4;
      *(short4*)&f1h[fo] = hv;
      *(short4*)&f1l[fo] = lv;
    }
  };

  auto conv2_part = [&](int half) {
    for (int s = 0; s < 5; ++s) {
      const short* wb = wp + (size_t)(8 + (half*5 + s)*2)*512;
      bf16x8 wh = *(const bf16x8*)(wb + pl*32 + 8*g);
      bf16x8 wl = *(const bf16x8*)(wb + 512 + pl*32 + 8*g);
      int pos = 2*s + (g >> 1);
      bool pv = pos < 9;
      int dy = pv ? pos/3 : 0, dx = pv ? pos%3 : 0;
      const int pb = (g&1)*3200;
      #pragma unroll
      for (int n = 0; n < 6; ++n) {
        int idx = (ryA[n] + dy)*20 + rxA[n] + dx;
        bf16x8 bh = {0,0,0,0,0,0,0,0}, bl = {0,0,0,0,0,0,0,0};
        if (pv) {
          int so = pb + idx*8;
          bh = *(const bf16x8*)&f1h[so];
          bl = *(const bf16x8*)&f1l[so];
        }
        acc2[n] = MFMA16(wh, bh, acc2[n], 0,0,0);
        acc2[n] = MFMA16(wh, bl, acc2[n], 0,0,0);
        acc2[n] = MFMA16(wl, bh, acc2[n], 0,0,0);
      }
    }
  };

  conv1_half(0);
  __syncthreads();
  conv2_part(0);
  __syncthreads();
  conv1_half(1);
  __syncthreads();
  conv2_part(1);
  #pragma unroll
  for (int n = 0; n < 6; ++n) {
    int G = wv + 4*n; if (G > 20) G = 20;
    int px = 16*G + pl;
    if (px < 324) {
      int gy = y0 - 1 + ryA[n], gx = x0 - 1 + rxA[n];
      bool ok = ((unsigned)gy < HH) && ((unsigned)gx < WW);
      short4 hv, lv;
      #pragma unroll
      for (int r = 0; r < 4; ++r) {
        float v = ok ? leaky_f(acc2[n][r]) : 0.f;
        short h, l; tsplit(v, h, l);
        ((short*)&hv)[r] = h;
        ((short*)&lv)[r] = l;
      }
      int fo = (g>>1)*2592 + px*8 + (g&1)*4;
      *(short4*)&f2h[fo] = hv;
      *(short4*)&f2l[fo] = lv;
    }
  }
  __syncthreads();

  // ---- conv3: 16->8 (plane = g&1) ----
  {
    f32x4 acc[4];
    float4 bb;
    if (g < 2) bb = *(const float4*)&b3[4*g];
    else { bb.x = 0.f; bb.y = 0.f; bb.z = 0.f; bb.w = 0.f; }
    #pragma unroll
    for (int n = 0; n < 4; ++n) acc[n] = f32x4{bb.x, bb.y, bb.z, bb.w};
    for (int s = 0; s < 5; ++s) {
      const short* wb = wp + (size_t)(28 + s*2)*512;
      bf16x8 wh = *(const bf16x8*)(wb + pl*32 + 8*g);
      bf16x8 wl = *(const bf16x8*)(wb + 512 + pl*32 + 8*g);
      int pos = 2*s + (g >> 1);
      bool pv = pos < 9;
      int dy = pv ? pos/3 : 0, dx = pv ? pos%3 : 0;
      const int pb = (g&1)*2592;
      #pragma unroll
      for (int n = 0; n < 4; ++n) {
        int px = 16*(wv + 4*n) + pl;
        int ry = px >> 4, rx = px & 15;
        int idx = (ry + dy)*18 + rx + dx;
        bf16x8 bh = {0,0,0,0,0,0,0,0}, bl = {0,0,0,0,0,0,0,0};
        if (pv) {
          int so = pb + idx*8;
          bh = *(const bf16x8*)&f2h[so];
          bl = *(const bf16x8*)&f2l[so];
        }
        acc[n] = MFMA16(wh, bh, acc[n], 0,0,0);
        acc[n] = MFMA16(wh, bl, acc[n], 0,0,0);
        acc[n] = MFMA16(wl, bh, acc[n], 0,0,0);
      }
    }
    #pragma unroll
    for (int n = 0; n < 4; ++n) {
      int px = 16*(wv + 4*n) + pl;
      int ry = px >> 4, rx = px & 15;
      size_t base = (size_t)(y0 + ry)*WW + (x0 + rx);
      #pragma unroll
      for (int r = 0; r < 4; ++r) {
        int oc = 4*g + r;
        if (oc < 8) f3[(size_t)oc*HWSZ + base] = acc[n][r];
      }
    }
  }
}

// ---------------- std maps: 32x32 tile, dual SATs, channel prefetch, fused histA ----------------
#define SATW 82
__device__ __forceinline__ float satv(const float* __restrict__ S, int r, int c) {
  return (r < 0 || c < 0) ? 0.f : S[r*SATW + c];
}
__device__ __forceinline__ float boxsum(const float* __restrict__ S, int r1, int r2, int c1, int c2) {
  return satv(S, r2, c2) - satv(S, r1-1, c2) - satv(S, r2, c1-1) + satv(S, r1-1, c1-1);
}

__global__ __launch_bounds__(256) void k_std(
    const float* __restrict__ f3, const float* __restrict__ wf,
    const float* __restrict__ bfp, float* __restrict__ fused, unsigned* __restrict__ ghA)
{
  __shared__ __align__(8) float S1[80*SATW];
  __shared__ __align__(8) float S2[80*SATW];
  const int tid = threadIdx.x;
  const int x0 = blockIdx.x * 32, y0 = blockIdx.y * 32;

  int off[25];
  #pragma unroll
  for (int it = 0; it < 25; ++it) {
    const int idx = tid + 256*it;
    const int r = idx / 80, cc = idx - r*80;
    int gy = y0 - 24 + r;  gy = gy < 0 ? -gy : (gy >= HH ? 2*HH - 2 - gy : gy);
    int gx = x0 - 24 + cc; gx = gx < 0 ? -gx : (gx >= WW ? 2*WW - 2 - gx : gx);
    off[it] = gy*WW + gx;
  }

  float pf[25];
  #pragma unroll
  for (int it = 0; it < 25; ++it) pf[it] = f3[off[it]];

  float acc0[4], acc1[4], acc2[4];
  #pragma unroll
  for (int k = 0; k < 4; ++k) { acc0[k] = 0.f; acc1[k] = 0.f; acc2[k] = 0.f; }

  for (int ch = 0; ch < 8; ++ch) {
    #pragma unroll
    for (int it = 0; it < 25; ++it) {
      const int idx = tid + 256*it;
      const int si = idx + 2*(idx/80);
      const float v = pf[it];
      S1[si] = v;
      S2[si] = v*v;
    }
    __syncthreads();
    if (ch < 7) {
      const float* fn = f3 + (size_t)(ch+1)*HWSZ;
      #pragma unroll
      for (int it = 0; it < 25; ++it) pf[it] = fn[off[it]];
    }
    if (tid < 160) {
      float* row = (tid >= 80 ? S2 + (tid-80)*SATW : S1 + tid*SATW);
      float run = 0.f;
      #pragma unroll
      for (int q = 0; q < 40; ++q) {
        float2 v = *(float2*)&row[q*2];
        float a = run + v.x;
        float b = a + v.y;
        float2 st = {a, b};
        *(float2*)&row[q*2] = st;
        run = b;
      }
    }
    __syncthreads();
    if (tid < 160) {
      float* Sc = (tid >= 80 ? S2 + (tid-80) : S1 + tid);
      float run = 0.f;
      #pragma unroll
      for (int g4 = 0; g4 < 20; ++g4) {
        float v0 = Sc[(g4*4+0)*SATW];
        float v1 = Sc[(g4*4+1)*SATW];
        float v2 = Sc[(g4*4+2)*SATW];
        float v3 = Sc[(g4*4+3)*SATW];
        run += v0; Sc[(g4*4+0)*SATW] = run;
        run += v1; Sc[(g4*4+1)*SATW] = run;
        run += v2; Sc[(g4*4+2)*SATW] = run;
        run += v3; Sc[(g4*4+3)*SATW] = run;
      }
    }
    __syncthreads();
    #pragma unroll
    for (int k = 0; k < 4; ++k) {
      const int px = tid + 256*k;
      const int py = px >> 5, xx = px & 31;
      {
        const float invn = 1.f/121.f;
        const float s1 = boxsum(S1, py+19, py+29, xx+19, xx+29);
        const float s2 = boxsum(S2, py+19, py+29, xx+19, xx+29);
        const float m = s1*invn;
        acc0[k] += sqrtf(fmaxf(s2*invn - m*m, 1e-6f));
      }
      {
        const float invn = 1.f/625.f;
        const float s1 = boxsum(S1, py+12, py+36, xx+12, xx+36);
        const float s2 = boxsum(S2, py+12, py+36, xx+12, xx+36);
        const float m = s1*invn;
        acc1[k] += sqrtf(fmaxf(s2*invn - m*m, 1e-6f));
      }
      {
        const float invn = 1.f/2401.f;
        const float s1 = boxsum(S1, py, py+48, xx, xx+48);
        const float s2 = boxsum(S2, py, py+48, xx, xx+48);
        const float m = s1*invn;
        acc2[k] += sqrtf(fmaxf(s2*invn - m*m, 1e-6f));
      }
    }
    __syncthreads();
  }

  unsigned* lh = (unsigned*)S1;
  for (int i = tid; i < 2048; i += 256) lh[i] = 0;
  __syncthreads();
  const float wv0 = wf[0], wv1 = wf[1], wv2 = wf[2], bv = bfp[0];
  #pragma unroll
  for (int k = 0; k < 4; ++k) {
    const int px = tid + 256*k;
    const int py = px >> 5, xx = px & 31;
    const float r0 = acc0[k]*0.125f, r1 = acc1[k]*0.125f, r2 = acc2[k]*0.125f;
    const float p0 = exp2f(0.8f*log2f(r0));
    const float p1 = exp2f(0.8f*log2f(r1));
    const float p2 = exp2f(0.8f*log2f(r2));
    float f = wv0*p0 + wv1*p1 + wv2*p2 + bv;
    f = fmaxf(f, 0.f);
    fused[(size_t)(y0 + py)*WW + (x0 + xx)] = f;
    atomicAdd(&lh[__float_as_uint(f) >> 21], 1u);
  }
  __syncthreads();
  for (int i = tid; i < 2048; i += 256) if (lh[i]) atomicAdd(&ghA[i], lh[i]);
}

// ---------------- radix select ----------------
__device__ bool scan_select(const unsigned* __restrict__ hist, int per, unsigned rank,
                            unsigned& bin, unsigned& inner) {
  const int lane = threadIdx.x & 63;
  const int base = lane * per;
  unsigned s = 0;
  for (int j = 0; j < per; ++j) s += hist[base + j];
  unsigned v = s;
  for (int off = 1; off < 64; off <<= 1) {
    unsigned n = __shfl_up(v, off, 64);
    if (lane >= off) v += n;
  }
  const unsigned excl = v - s;
  const bool has = (rank >= excl) && (rank < v);
  const unsigned long long m = __ballot(has);
  const int L = __ffsll(m) - 1;
  if (lane == L) {
    unsigned rem = rank - excl;
    for (int j = 0; j < per; ++j) {
      const unsigned c = hist[base + j];
      if (rem < c) { bin = (unsigned)(base + j); inner = rem; return true; }
      rem -= c;
    }
  }
  return false;
}

__device__ __forceinline__ float seg_sig(float ns) {
  ns = fminf(fmaxf(ns, 0.f), 1.f);
  float res;
  if (ns < 0.25f)      res = 0.4f / (1.f + expf(-(10.f*ns - 1.5f)));
  else if (ns <= 0.6f) res = 0.5f / (1.f + expf(-(20.f*ns - 8.f))) + 0.25f;
  else                 res = 0.3f / (1.f + expf(-(8.f*ns - 1.f))) + 0.7f;
  return res;
}

__device__ void tail_thresholds(const Scalars* sc, const float* cwp,
    float q_low, float q_high, float* ths) {
  const float c0 = cwp[0], c1 = cwp[1], c2 = cwp[2], c3 = cwp[3];
  const float mx = fmaxf(fmaxf(c0, c1), fmaxf(c2, c3));
  const float e0 = expf(c0 - mx), e1 = expf(c1 - mx), e2 = expf(c2 - mx), e3 = expf(c3 - mx);
  const float es = e0 + e1 + e2 + e3;
  const float cw[4] = {e0/es, e1/es, e2/es, e3/es};
  const double N = (double)HWSZ;
  float lsum = 0.f, usum = 0.f;
  for (int c = 0; c < 4; ++c) {
    double var = ((double)sc->gsumsq[c] - (double)sc->gsum[c]*(double)sc->gsum[c]/N) / (N - 1.0);
    if (var < 0.0) var = 0.0;
    const float gs = (float)sqrt(var);
    const float gf = fminf(fmaxf(gs*5.f, 0.5f), 2.f);
    float lt = 0.05f*gf, ut = 0.2f*gf;
    const float cs = cw[c]*gs;
    const float cf = fminf(fmaxf(cs*2.f, 0.8f), 1.2f);
    lt *= cf; ut *= cf;
    lsum += lt; usum += ut;
  }
  float l_th = 0.5f*(lsum*0.25f + q_low);
  float u_th = 0.5f*(usum*0.25f + q_high);
  if (u_th - l_th < 0.01f) u_th = l_th + 0.01f;
  ths[0] = l_th; ths[1] = u_th;
}

__global__ __launch_bounds__(256) void k_histB(const float* __restrict__ fused,
    const unsigned* __restrict__ ghA, unsigned* __restrict__ gh,
    unsigned r0, unsigned r1, unsigned r2, unsigned r3) {
  __shared__ unsigned lh[4*2048];
  __shared__ unsigned t1s[4];
  {
    const int w = threadIdx.x >> 6;
    const unsigned rk = (w == 0) ? r0 : (w == 1) ? r1 : (w == 2) ? r2 : r3;
    unsigned bin, inner;
    if (scan_select(ghA, 32, rk, bin, inner)) t1s[w] = bin;
  }
  for (int i = threadIdx.x; i < 8192; i += 256) lh[i] = 0;
  __syncthreads();
  const unsigned t0 = t1s[0], t1 = t1s[1], t2 = t1s[2], t3 = t1s[3];
  for (int i = blockIdx.x*256 + threadIdx.x; i < HWSZ; i += 512*256) {
    const unsigned u = __float_as_uint(fused[i]);
    const unsigned p = u >> 21, b = (u >> 10) & 2047u;
    if (p == t0) atomicAdd(&lh[b], 1u);
    if (p == t1) atomicAdd(&lh[2048 + b], 1u);
    if (p == t2) atomicAdd(&lh[4096 + b], 1u);
    if (p == t3) atomicAdd(&lh[6144 + b], 1u);
  }
  __syncthreads();
  for (int i = threadIdx.x; i < 8192; i += 256) if (lh[i]) atomicAdd(&gh[i], lh[i]);
}

// ---------------- apply: B-level quantile (bin midpoint) + thresholds + sigmoid ----------------
__global__ __launch_bounds__(256) void k_apply(const float* __restrict__ fused,
    const Scalars* __restrict__ sc, const float* __restrict__ cwp,
    const unsigned* __restrict__ ghA, const unsigned* __restrict__ ghB,
    float* __restrict__ out,
    unsigned r0, unsigned r1, unsigned r2, unsigned r3, float fr_lo, float fr_hi) {
  __shared__ unsigned t1s[4], in1s[4];
  __shared__ float vqs[4];
  __shared__ float ths[2];
  const int w = threadIdx.x >> 6;
  {
    const unsigned rk = (w == 0) ? r0 : (w == 1) ? r1 : (w == 2) ? r2 : r3;
    unsigned bin, inner;
    if (scan_select(ghA, 32, rk, bin, inner)) { t1s[w] = bin; in1s[w] = inner; }
  }
  __syncthreads();
  {
    unsigned bin, inner;
    if (scan_select(ghB + w*2048, 32, in1s[w], bin, inner)) {
      // value known to bits 31:10; use bin midpoint (error <= 512 ulp ~ 6e-5 rel)
      vqs[w] = __uint_as_float((((t1s[w] << 11) | bin) << 10) | 512u);
    }
  }
  __syncthreads();
  if (threadIdx.x == 0) {
    const float q_low  = vqs[0] + fr_lo * (vqs[1] - vqs[0]);
    const float q_high = vqs[2] + fr_hi * (vqs[3] - vqs[2]);
    tail_thresholds(sc, cwp, q_low, q_high, ths);
  }
  __syncthreads();
  const float l = ths[0], u = ths[1];
  const float d = u - l;
  const int i = blockIdx.x*256 + threadIdx.x;
  if (i < HWSZ/4) {
    const float4 v = ((const float4*)fused)[i];
    float4 r;
    r.x = seg_sig((v.x - l) / d);
    r.y = seg_sig((v.y - l) / d);
    r.z = seg_sig((v.z - l) / d);
    r.w = seg_sig((v.w - l) / d);
    ((float4*)out)[i] = r;
  }
}

extern "C" void kernel_launch(void* const* d_in, const int* in_sizes, int n_in,
                              void* d_out, int out_size, void* d_ws, size_t ws_size,
                              hipStream_t stream) {
  const float* x  = (const float*)d_in[0];
  const float* w1 = (const float*)d_in[1];
  const float* b1 = (const float*)d_in[2];
  const float* w2 = (const float*)d_in[3];
  const float* b2 = (const float*)d_in[4];
  const float* w3 = (const float*)d_in[5];
  const float* b3 = (const float*)d_in[6];
  const float* wf = (const float*)d_in[7];
  const float* bf = (const float*)d_in[8];
  const float* cw = (const float*)d_in[9];
  char* ws = (char*)d_ws;
  if (ws_size < WS_NEEDED) return;

  float*    f3    = (float*)(ws + OFF_F3);
  float*    fused = (float*)(ws + OFF_FUSED);
  Scalars*  sc    = (Scalars*)(ws + OFF_SC);
  unsigned* ghA   = (unsigned*)(ws + OFF_GHA);
  unsigned* ghB   = (unsigned*)(ws + OFF_GHB);
  short*    wp    = (short*)(ws + OFF_WP);
  unsigned* zr    = (unsigned*)(ws + OFF_SC);

  const double p_lo = 0.3 * (double)(HWSZ - 1);
  const double p_hi = 0.7 * (double)(HWSZ - 1);
  const unsigned k0 = (unsigned)p_lo, k1 = (unsigned)p_hi;
  const float fr_lo = (float)(p_lo - (double)k0);
  const float fr_hi = (float)(p_hi - (double)k1);

  k_pack <<<76, 256, 0, stream>>>(w1, w2, w3, wp, zr);
  k_conv <<<dim3(96, 96), 256, 0, stream>>>(x, b1, b2, b3, wp, f3, sc);
  k_std  <<<dim3(48, 48), 256, 0, stream>>>(f3, wf, bf, fused, ghA);
  k_histB<<<512, 256, 0, stream>>>(fused, ghA, ghB, k0, k0 + 1, k1, k1 + 1);
  k_apply<<<(HWSZ/4 + 255)/256, 256, 0, stream>>>(fused, sc, cw, ghA, ghB,
      (float*)d_out, k0, k0 + 1, k1, k1 + 1, fr_lo, fr_hi);
}